// Round 14
// baseline (97.804 us; speedup 1.0000x reference)
//
#include <hip/hip_runtime.h>
#include <hip/hip_bf16.h>

typedef __attribute__((ext_vector_type(2)))  float f32x2;
typedef __attribute__((ext_vector_type(8)))  float f32x8;
typedef __attribute__((ext_vector_type(16))) float f32x16;
typedef __attribute__((ext_vector_type(2)))  __bf16 bf16x2;
typedef __attribute__((ext_vector_type(8)))  __bf16 bf16x8;
typedef __attribute__((ext_vector_type(4)))  unsigned int u32x4;

// f32x8 -> bf16x8, compiler-lowered (cold path).
static __device__ __forceinline__ bf16x8 cvt8(f32x8 v) {
    return __builtin_convertvector(v, bf16x8);
}
// f32 pair -> u32 of 2 bf16 (RNE), compiler-lowered packed cvt.
static __device__ __forceinline__ unsigned int pkcvt(f32x2 v) {
    return __builtin_bit_cast(unsigned int, __builtin_convertvector(v, bf16x2));
}
static __device__ __forceinline__ f32x2 max2(f32x2 v) {
    const f32x2 z = {0.f, 0.f};
    return __builtin_elementwise_max(v, z);
}

#define MFMA32(A, B, C) __builtin_amdgcn_mfma_f32_32x32x16_bf16((A), (B), (C), 0, 0, 0)

// R13 compute, flat-grid launch (one 128-pt chunk per 256-thread block).
// kperm(h,i) = (i&3) + 8*(i>>2) + 4h : 32x32 D-frag row in reg i, lane-group h.
// A2 K-order permuted by kperm at init so D1 regs 0..7 pack directly into the
// next B-frag (no cross-lane ops). Layer 3 in packed-f32 VALU with w3/b2
// kperm'd; lane-half partials folded with __shfl_xor(.,32).
__global__ __launch_bounds__(256, 3) void mlp3_mfma32(
    const float* __restrict__ x,
    const float* __restrict__ W1, const float* __restrict__ b1,
    const float* __restrict__ W2, const float* __restrict__ b2,
    const float* __restrict__ W3, const float* __restrict__ b3,
    float* __restrict__ out, int n)
{
    const int tid  = (int)threadIdx.x;
    const int lane = tid & 63;
    const int row  = lane & 31;   // A-frag row / B col (point)
    const int h    = lane >> 5;   // K-half selector in frag layouts
    const int wv   = tid >> 6;

    // ---- weight fragments / constants (resident) ----
    bf16x8 a1[3], a2[3];
    f32x2  w3p[3][4], b2p[3][4];
    #pragma unroll
    for (int e = 0; e < 3; ++e) {
        f32x8 t = {0.f,0.f,0.f,0.f,0.f,0.f,0.f,0.f};
        if (h == 0 && row < 16) {
            t[0] = W1[e * 32 + row];        // k=0: W1[e][0][row]
            t[1] = W1[e * 32 + 16 + row];   // k=1: W1[e][1][row]
            t[2] = b1[e * 16 + row];        // k=2: b1 (x K-slot 2 = 1.0)
        }
        a1[e] = cvt8(t);
        f32x8 t2 = {0.f,0.f,0.f,0.f,0.f,0.f,0.f,0.f};
        if (row < 16) {
            #pragma unroll
            for (int i = 0; i < 8; ++i) {
                const int k = (i & 3) + 8 * (i >> 2) + 4 * h;   // kperm(h,i)
                t2[i] = W2[e * 256 + k * 16 + row];
            }
        }
        a2[e] = cvt8(t2);
        #pragma unroll
        for (int j = 0; j < 4; ++j) {
            const int i0 = 2 * j, i1 = 2 * j + 1;
            const int k0 = (i0 & 3) + 8 * (i0 >> 2) + 4 * h;
            const int k1 = (i1 & 3) + 8 * (i1 >> 2) + 4 * h;
            w3p[e][j] = (f32x2){ W3[e * 16 + k0], W3[e * 16 + k1] };
            b2p[e][j] = (f32x2){ b2[e * 16 + k0], b2[e * 16 + k1] };
        }
    }
    const float b30 = b3[0], b31 = b3[1], b32 = b3[2];
    f32x16 zz;
    #pragma unroll
    for (int r = 0; r < 16; ++r) zz[r] = 0.f;

    const int cb   = (int)blockIdx.x;        // one 128-pt chunk per block
    const int xoff = (wv * 32 + row) * 8;    // bytes into 1024B x-chunk
    const int ooff = (wv * 32 + row) * 12;   // bytes into 1536B out-chunk (lane<32)

    const float2 xv = *reinterpret_cast<const float2*>(
        (const char*)x + (size_t)cb * 1024 + xoff);

    // B1: k-slots {x0, x1, 1.0, 0...}; h=1 half garbage-safe (A1 zero there)
    u32x4 bu = { pkcvt((f32x2){xv.x, xv.y}), 0x3F80u, 0u, 0u };
    const bf16x8 bx = __builtin_bit_cast(bf16x8, bu);

    float ys[3];
    #pragma unroll
    for (int e = 0; e < 3; ++e) {
        f32x16 t1 = MFMA32(a1[e], bx, zz);
        u32x4 bhw;
        #pragma unroll
        for (int j = 0; j < 4; ++j)
            bhw[j] = pkcvt(max2((f32x2){ t1[2*j], t1[2*j+1] }));
        const bf16x8 bh = __builtin_bit_cast(bf16x8, bhw);

        f32x16 t2 = MFMA32(a2[e], bh, zz);
        f32x2 yp = {0.f, 0.f};
        #pragma unroll
        for (int j = 0; j < 4; ++j) {
            f32x2 q = max2((f32x2){ t2[2*j], t2[2*j+1] } + b2p[e][j]);
            yp += w3p[e][j] * q;              // packed fma
        }
        const float ysum = yp[0] + yp[1];            // this lane-half's 8 k's
        ys[e] = ysum + __shfl_xor(ysum, 32, 64);     // + other half's 8 k's
    }

    if (lane < 32) {
        *reinterpret_cast<float3*>((char*)out + (size_t)cb * 1536 + ooff) =
            make_float3(ys[0] + b30, ys[1] + b31, ys[2] + b32);
    }
}

extern "C" void kernel_launch(void* const* d_in, const int* in_sizes, int n_in,
                              void* d_out, int out_size, void* d_ws, size_t ws_size,
                              hipStream_t stream) {
    const float* x  = (const float*)d_in[0];
    const float* W1 = (const float*)d_in[1];
    const float* b1 = (const float*)d_in[2];
    const float* W2 = (const float*)d_in[3];
    const float* b2 = (const float*)d_in[4];
    const float* W3 = (const float*)d_in[5];
    const float* b3 = (const float*)d_in[6];
    float* out = (float*)d_out;
    (void)d_ws; (void)ws_size; (void)n_in; (void)out_size;

    const int n = in_sizes[0] / 2;   // 4194304 points
    const int block = 256;
    const int grid = n >> 7;         // 32768 blocks, one 128-pt chunk each

    mlp3_mfma32<<<grid, block, 0, stream>>>(x, W1, b1, W2, b2, W3, b3, out, n);
}

// Round 15
// 50.462 us; speedup vs baseline: 1.9382x; 1.9382x over previous
//
#include <hip/hip_runtime.h>
#include <hip/hip_bf16.h>

typedef __attribute__((ext_vector_type(2)))  float f32x2;
typedef __attribute__((ext_vector_type(8)))  float f32x8;
typedef __attribute__((ext_vector_type(16))) float f32x16;
typedef __attribute__((ext_vector_type(2)))  __bf16 bf16x2;
typedef __attribute__((ext_vector_type(8)))  __bf16 bf16x8;
typedef __attribute__((ext_vector_type(4)))  unsigned int u32x4;

static __device__ __forceinline__ bf16x8 cvt8(f32x8 v) {
    return __builtin_convertvector(v, bf16x8);
}
static __device__ __forceinline__ unsigned int pkcvt(f32x2 v) {
    return __builtin_bit_cast(unsigned int, __builtin_convertvector(v, bf16x2));
}
static __device__ __forceinline__ f32x2 max2(f32x2 v) {
    const f32x2 z = {0.f, 0.f};
    return __builtin_elementwise_max(v, z);
}
// bf16x2 (packed u32) -> f32x2: pure bit ops, 2 insts.
static __device__ __forceinline__ f32x2 bfexp(unsigned int u) {
    f32x2 r;
    r[0] = __builtin_bit_cast(float, u << 16);
    r[1] = __builtin_bit_cast(float, u & 0xFFFF0000u);
    return r;
}

#define MFMA32(A, B, C) __builtin_amdgcn_mfma_f32_32x32x16_bf16((A), (B), (C), 0, 0, 0)

// kperm(h,i) = (i&3) + 8*(i>>2) + 4h : 32x32 D-frag row held in reg i of
// lane-group h (bijection on [0,16)). A2/A3 K-orders are kperm'd at init so
// D regs pack directly into the next B operand — zero cross-lane ops.
// Dual-head MFMA1: A1d rows 0-15 = head0, rows 16-31 = head1 (B = x shared);
// t1d regs 0-7 -> bh0, regs 8-15 -> bh1 (same kperm pattern, shifted rows).
// Head2 in a second (half-empty) MFMA1. Layer3: row-selective kperm'd A3,
// chained C across heads; lanes<32 end with (y0,y1,y2) in regs 0-2.
__global__ __launch_bounds__(256, 4) void mlp3_mfma32(
    const float* __restrict__ x,
    const float* __restrict__ W1, const float* __restrict__ b1,
    const float* __restrict__ W2, const float* __restrict__ b2,
    const float* __restrict__ W3, const float* __restrict__ b3,
    float* __restrict__ out, int n)
{
    const int tid  = (int)threadIdx.x;
    const int lane = tid & 63;
    const int row  = lane & 31;   // A-frag row / B col (point)
    const int h    = lane >> 5;   // K-half selector
    const int wv   = tid >> 6;

    // ---- weight fragments / constants (resident; total budget ~124 regs) ----
    bf16x8 a1d, a1s;
    {
        f32x8 t = {0.f,0.f,0.f,0.f,0.f,0.f,0.f,0.f};
        if (h == 0) {                       // heads 0,1: row = hd*16 + j
            const int hd = row >> 4, j = row & 15;
            t[0] = W1[hd * 32 + j];         // k=0: W1[hd][0][j]
            t[1] = W1[hd * 32 + 16 + j];    // k=1: W1[hd][1][j]
            t[2] = b1[hd * 16 + j];         // k=2: b1 (x K-slot 2 = 1.0)
        }
        a1d = cvt8(t);
        f32x8 s = {0.f,0.f,0.f,0.f,0.f,0.f,0.f,0.f};
        if (h == 0 && row < 16) {           // head 2 in rows 0..15
            s[0] = W1[64 + row];
            s[1] = W1[80 + row];
            s[2] = b1[32 + row];
        }
        a1s = cvt8(s);
    }
    bf16x8 a2[3], a3[3];
    u32x4  b2pk[3];
    #pragma unroll
    for (int e = 0; e < 3; ++e) {
        f32x8 t2v = {0.f,0.f,0.f,0.f,0.f,0.f,0.f,0.f};
        if (row < 16) {
            #pragma unroll
            for (int i = 0; i < 8; ++i) {
                const int k = (i & 3) + 8 * (i >> 2) + 4 * h;   // kperm(h,i)
                t2v[i] = W2[e * 256 + k * 16 + row];
            }
        }
        a2[e] = cvt8(t2v);
        f32x8 t3 = {0.f,0.f,0.f,0.f,0.f,0.f,0.f,0.f};
        if (row == e) {
            #pragma unroll
            for (int i = 0; i < 8; ++i) {
                const int k = (i & 3) + 8 * (i >> 2) + 4 * h;
                t3[i] = W3[e * 16 + k];
            }
        }
        a3[e] = cvt8(t3);
        #pragma unroll
        for (int j = 0; j < 4; ++j) {
            const int k0 = ((2*j) & 3) + 8 * ((2*j) >> 2) + 4 * h;
            const int k1 = ((2*j+1) & 3) + 8 * ((2*j+1) >> 2) + 4 * h;
            b2pk[e][j] = pkcvt((f32x2){ b2[e * 16 + k0], b2[e * 16 + k1] });
        }
    }
    const float b30 = b3[0], b31 = b3[1], b32 = b3[2];
    f32x16 zz;
    #pragma unroll
    for (int r = 0; r < 16; ++r) zz[r] = 0.f;

    const int xoff = (wv * 32 + row) * 8;    // bytes into 1024B x-chunk
    const int ooff = (wv * 32 + row) * 12;   // bytes into 1536B out-chunk (lane<32)

    const int nblk   = n >> 7;               // 128 points per block-iter
    const int stride = (int)gridDim.x;

    int cb = (int)blockIdx.x;
    float2 xv = *reinterpret_cast<const float2*>((const char*)x + (size_t)cb * 1024 + xoff);

    while (true) {
        const int nb = cb + stride;
        const bool more = nb < nblk;
        float2 xn;
        if (more)                             // prefetch next iter's x
            xn = *reinterpret_cast<const float2*>((const char*)x + (size_t)nb * 1024 + xoff);

        // B1 k-slots {x0, x1, 1.0, 0...}
        u32x4 bu = { pkcvt((f32x2){xv.x, xv.y}), 0x3F80u, 0u, 0u };
        const bf16x8 bx = __builtin_bit_cast(bf16x8, bu);

        // Layer 1: heads 0,1 in one MFMA; head 2 in a second.
        f32x16 t1d = MFMA32(a1d, bx, zz);
        f32x16 t1s = MFMA32(a1s, bx, zz);
        u32x4 w0, w1, w2;
        #pragma unroll
        for (int j = 0; j < 4; ++j) {
            w0[j] = pkcvt(max2((f32x2){ t1d[2*j],     t1d[2*j + 1] }));
            w1[j] = pkcvt(max2((f32x2){ t1d[8 + 2*j], t1d[8 + 2*j + 1] }));
            w2[j] = pkcvt(max2((f32x2){ t1s[2*j],     t1s[2*j + 1] }));
        }
        const bf16x8 bh0 = __builtin_bit_cast(bf16x8, w0);
        const bf16x8 bh1 = __builtin_bit_cast(bf16x8, w1);
        const bf16x8 bh2 = __builtin_bit_cast(bf16x8, w2);

        // Layers 2+3 per head, y chained through MFMA3's C.
        f32x16 y;
        #pragma unroll
        for (int e = 0; e < 3; ++e) {
            const bf16x8 bh = (e == 0) ? bh0 : ((e == 1) ? bh1 : bh2);
            f32x16 t2 = MFMA32(a2[e], bh, zz);
            u32x4 bw;
            #pragma unroll
            for (int j = 0; j < 4; ++j) {
                f32x2 q = (f32x2){ t2[2*j], t2[2*j + 1] } + bfexp(b2pk[e][j]);
                bw[j] = pkcvt(max2(q));
            }
            const bf16x8 bt = __builtin_bit_cast(bf16x8, bw);
            y = MFMA32(a3[e], bt, (e == 0) ? zz : y);
        }

        if (lane < 32) {                      // rows 0..2 = heads, regs 0..2
            *reinterpret_cast<float3*>((char*)out + (size_t)cb * 1536 + ooff) =
                make_float3(y[0] + b30, y[1] + b31, y[2] + b32);
        }

        if (!more) break;
        cb = nb;
        xv = xn;
    }
}

extern "C" void kernel_launch(void* const* d_in, const int* in_sizes, int n_in,
                              void* d_out, int out_size, void* d_ws, size_t ws_size,
                              hipStream_t stream) {
    const float* x  = (const float*)d_in[0];
    const float* W1 = (const float*)d_in[1];
    const float* b1 = (const float*)d_in[2];
    const float* W2 = (const float*)d_in[3];
    const float* b2 = (const float*)d_in[4];
    const float* W3 = (const float*)d_in[5];
    const float* b3 = (const float*)d_in[6];
    float* out = (float*)d_out;
    (void)d_ws; (void)ws_size; (void)n_in; (void)out_size;

    const int n = in_sizes[0] / 2;   // 4194304 points (32768 * 128)
    const int block = 256;
    const int grid = 2048;           // persistent: 16 chunk-iterations per block

    mlp3_mfma32<<<grid, block, 0, stream>>>(x, W1, b1, W2, b2, W3, b3, out, n);
}

// Round 16
// 46.506 us; speedup vs baseline: 2.1030x; 1.0851x over previous
//
#include <hip/hip_runtime.h>
#include <hip/hip_bf16.h>

typedef __attribute__((ext_vector_type(2)))  float f32x2;
typedef __attribute__((ext_vector_type(8)))  float f32x8;
typedef __attribute__((ext_vector_type(16))) float f32x16;
typedef __attribute__((ext_vector_type(2)))  __bf16 bf16x2;
typedef __attribute__((ext_vector_type(8)))  __bf16 bf16x8;
typedef __attribute__((ext_vector_type(4)))  unsigned int u32x4;

static __device__ __forceinline__ bf16x8 cvt8(f32x8 v) {
    return __builtin_convertvector(v, bf16x8);
}
static __device__ __forceinline__ unsigned int pkcvt(f32x2 v) {
    return __builtin_bit_cast(unsigned int, __builtin_convertvector(v, bf16x2));
}
static __device__ __forceinline__ f32x2 max2(f32x2 v) {
    const f32x2 z = {0.f, 0.f};
    return __builtin_elementwise_max(v, z);
}

#define MFMA32(A, B, C) __builtin_amdgcn_mfma_f32_32x32x16_bf16((A), (B), (C), 0, 0, 0)

// kperm(h,i) = (i&3) + 8*(i>>2) + 4h : 32x32 D-frag row held in reg i of
// lane-group h (bijection on [0,16)). A2/A3 K-orders kperm'd at init so D regs
// pack directly into the next B operand — zero cross-lane ops (R11/R15 valid).
// Dual-head MFMA1 (R15): A1d rows 0-15 = head0, 16-31 = head1; D regs 8-15
// hold rows 16+kperm(h,i). Layer3: row-selective kperm'd A3, chained C.
// NEW (R16): software-pipelined store — y extracted to `pend` at iter end,
// store ISSUED at the top of the next iter, so the vmcnt drain (pend reuse)
// is covered by the 8-MFMA block instead of stalling the loop head.
__global__ __launch_bounds__(256, 4) void mlp3_mfma32(
    const float* __restrict__ x,
    const float* __restrict__ W1, const float* __restrict__ b1,
    const float* __restrict__ W2, const float* __restrict__ b2,
    const float* __restrict__ W3, const float* __restrict__ b3,
    float* __restrict__ out, int n)
{
    const int tid  = (int)threadIdx.x;
    const int lane = tid & 63;
    const int row  = lane & 31;   // A-frag row / B col (point)
    const int h    = lane >> 5;   // K-half selector
    const int wv   = tid >> 6;

    // ---- weight fragments / constants (resident) ----
    bf16x8 a1d, a1s;
    {
        f32x8 t = {0.f,0.f,0.f,0.f,0.f,0.f,0.f,0.f};
        if (h == 0) {                       // heads 0,1: row = hd*16 + j
            const int hd = row >> 4, j = row & 15;
            t[0] = W1[hd * 32 + j];
            t[1] = W1[hd * 32 + 16 + j];
            t[2] = b1[hd * 16 + j];         // k=2: b1 (x K-slot 2 = 1.0)
        }
        a1d = cvt8(t);
        f32x8 s = {0.f,0.f,0.f,0.f,0.f,0.f,0.f,0.f};
        if (h == 0 && row < 16) {           // head 2 in rows 0..15
            s[0] = W1[64 + row];
            s[1] = W1[80 + row];
            s[2] = b1[32 + row];
        }
        a1s = cvt8(s);
    }
    bf16x8 a2[3], a3[3];
    f32x2  b2p[3][4];
    #pragma unroll
    for (int e = 0; e < 3; ++e) {
        f32x8 t2v = {0.f,0.f,0.f,0.f,0.f,0.f,0.f,0.f};
        if (row < 16) {
            #pragma unroll
            for (int i = 0; i < 8; ++i) {
                const int k = (i & 3) + 8 * (i >> 2) + 4 * h;   // kperm(h,i)
                t2v[i] = W2[e * 256 + k * 16 + row];
            }
        }
        a2[e] = cvt8(t2v);
        f32x8 t3 = {0.f,0.f,0.f,0.f,0.f,0.f,0.f,0.f};
        if (row == e) {
            #pragma unroll
            for (int i = 0; i < 8; ++i) {
                const int k = (i & 3) + 8 * (i >> 2) + 4 * h;
                t3[i] = W3[e * 16 + k];
            }
        }
        a3[e] = cvt8(t3);
        #pragma unroll
        for (int j = 0; j < 4; ++j) {
            const int k0 = ((2*j) & 3) + 8 * ((2*j) >> 2) + 4 * h;
            const int k1 = ((2*j+1) & 3) + 8 * ((2*j+1) >> 2) + 4 * h;
            b2p[e][j] = (f32x2){ b2[e * 16 + k0], b2[e * 16 + k1] };
        }
    }
    const float b30 = b3[0], b31 = b3[1], b32 = b3[2];
    f32x16 zz;
    #pragma unroll
    for (int r = 0; r < 16; ++r) zz[r] = 0.f;

    const int xoff = (wv * 32 + row) * 8;    // bytes into 1024B x-chunk
    const int ooff = (wv * 32 + row) * 12;   // bytes into 1536B out-chunk (lane<32)

    const int nblk   = n >> 7;               // 128 points per block-iter
    const int stride = (int)gridDim.x;

    int cb = (int)blockIdx.x;
    float2 xv = *reinterpret_cast<const float2*>((const char*)x + (size_t)cb * 1024 + xoff);

    float3 pend;
    char*  paddr = nullptr;
    bool   pendv = false;

    while (true) {
        const int nb = cb + stride;
        const bool more = nb < nblk;
        float2 xn;
        if (more)                             // prefetch next iter's x
            xn = *reinterpret_cast<const float2*>((const char*)x + (size_t)nb * 1024 + xoff);

        // Issue previous iteration's store NOW: its drain deadline (pend
        // overwrite) is 8 MFMAs away instead of at the loop head.
        if (pendv && lane < 32)
            *reinterpret_cast<float3*>(paddr) = pend;

        // B1 k-slots {x0, x1, 1.0, 0...}
        u32x4 bu = { pkcvt((f32x2){xv.x, xv.y}), 0x3F80u, 0u, 0u };
        const bf16x8 bx = __builtin_bit_cast(bf16x8, bu);

        // Layer 1: heads 0,1 in one MFMA; head 2 in a second.
        f32x16 t1d = MFMA32(a1d, bx, zz);
        f32x16 t1s = MFMA32(a1s, bx, zz);
        u32x4 w0, w1, w2;
        #pragma unroll
        for (int j = 0; j < 4; ++j) {
            w0[j] = pkcvt(max2((f32x2){ t1d[2*j],     t1d[2*j + 1] }));
            w1[j] = pkcvt(max2((f32x2){ t1d[8 + 2*j], t1d[8 + 2*j + 1] }));
            w2[j] = pkcvt(max2((f32x2){ t1s[2*j],     t1s[2*j + 1] }));
        }
        const bf16x8 bh0 = __builtin_bit_cast(bf16x8, w0);
        const bf16x8 bh1 = __builtin_bit_cast(bf16x8, w1);
        const bf16x8 bh2 = __builtin_bit_cast(bf16x8, w2);

        // Layers 2+3 per head, y chained through MFMA3's C.
        f32x16 y;
        #pragma unroll
        for (int e = 0; e < 3; ++e) {
            const bf16x8 bh = (e == 0) ? bh0 : ((e == 1) ? bh1 : bh2);
            f32x16 t2 = MFMA32(a2[e], bh, zz);
            u32x4 bw;
            #pragma unroll
            for (int j = 0; j < 4; ++j) {
                f32x2 q = max2((f32x2){ t2[2*j], t2[2*j + 1] } + b2p[e][j]);
                bw[j] = pkcvt(q);
            }
            const bf16x8 bt = __builtin_bit_cast(bf16x8, bw);
            y = MFMA32(a3[e], bt, (e == 0) ? zz : y);
        }

        // Extract this iter's result; stored at the top of the next iter.
        pend  = make_float3(y[0] + b30, y[1] + b31, y[2] + b32);
        paddr = (char*)out + (size_t)cb * 1536 + ooff;
        pendv = true;

        if (!more) break;
        cb = nb;
        xv = xn;
    }

    if (pendv && lane < 32)
        *reinterpret_cast<float3*>(paddr) = pend;
}

extern "C" void kernel_launch(void* const* d_in, const int* in_sizes, int n_in,
                              void* d_out, int out_size, void* d_ws, size_t ws_size,
                              hipStream_t stream) {
    const float* x  = (const float*)d_in[0];
    const float* W1 = (const float*)d_in[1];
    const float* b1 = (const float*)d_in[2];
    const float* W2 = (const float*)d_in[3];
    const float* b2 = (const float*)d_in[4];
    const float* W3 = (const float*)d_in[5];
    const float* b3 = (const float*)d_in[6];
    float* out = (float*)d_out;
    (void)d_ws; (void)ws_size; (void)n_in; (void)out_size;

    const int n = in_sizes[0] / 2;   // 4194304 points (32768 * 128)
    const int block = 256;
    const int grid = 2048;           // persistent: 16 chunk-iterations per block

    mlp3_mfma32<<<grid, block, 0, stream>>>(x, W1, b1, W2, b2, W3, b3, out, n);
}

// Round 17
// 45.448 us; speedup vs baseline: 2.1520x; 1.0233x over previous
//
#include <hip/hip_runtime.h>
#include <hip/hip_bf16.h>

typedef __attribute__((ext_vector_type(2)))  float f32x2;
typedef __attribute__((ext_vector_type(8)))  float f32x8;
typedef __attribute__((ext_vector_type(16))) float f32x16;
typedef __attribute__((ext_vector_type(2)))  __bf16 bf16x2;
typedef __attribute__((ext_vector_type(8)))  __bf16 bf16x8;
typedef __attribute__((ext_vector_type(4)))  unsigned int u32x4;

static __device__ __forceinline__ bf16x8 cvt8(f32x8 v) {
    return __builtin_convertvector(v, bf16x8);
}
static __device__ __forceinline__ unsigned int pkcvt(f32x2 v) {
    return __builtin_bit_cast(unsigned int, __builtin_convertvector(v, bf16x2));
}
static __device__ __forceinline__ f32x2 max2(f32x2 v) {
    const f32x2 z = {0.f, 0.f};
    return __builtin_elementwise_max(v, z);
}
// packed bf16 pair (u32) -> f32x2, 2 bit-insts (R15-validated).
static __device__ __forceinline__ f32x2 bfexp(unsigned int u) {
    f32x2 r;
    r[0] = __builtin_bit_cast(float, u << 16);
    r[1] = __builtin_bit_cast(float, u & 0xFFFF0000u);
    return r;
}

#define MFMA32(A, B, C) __builtin_amdgcn_mfma_f32_32x32x16_bf16((A), (B), (C), 0, 0, 0)

// kperm(h,i) = (i&3) + 8*(i>>2) + 4h : 32x32 D-frag row held in reg i of
// lane-group h (bijection on [0,16)). A2/A3 K-orders kperm'd at init so D regs
// pack directly into the next B operand — zero cross-lane ops.
// R17: REGISTER DIET. One shared f32x16 temp `t` (L1-head01 consumed before
// L1-head2 issues); b2 packed bf16 (12 regs); running pointers. Target: unified
// VGPR+acc total <= 128 -> 4 waves/SIMD (R16 was ~136 -> 2.6 waves, occ 32%).
__global__ __launch_bounds__(256, 4) void mlp3_mfma32(
    const float* __restrict__ x,
    const float* __restrict__ W1, const float* __restrict__ b1,
    const float* __restrict__ W2, const float* __restrict__ b2,
    const float* __restrict__ W3, const float* __restrict__ b3,
    float* __restrict__ out, int n)
{
    const int tid  = (int)threadIdx.x;
    const int lane = tid & 63;
    const int row  = lane & 31;   // A-frag row / B col (point)
    const int h    = lane >> 5;   // K-half selector
    const int wv   = tid >> 6;

    // ---- weight fragments / constants (resident) ----
    bf16x8 a1d, a1s;
    {
        f32x8 t = {0.f,0.f,0.f,0.f,0.f,0.f,0.f,0.f};
        if (h == 0) {                       // heads 0,1: row = hd*16 + j
            const int hd = row >> 4, j = row & 15;
            t[0] = W1[hd * 32 + j];
            t[1] = W1[hd * 32 + 16 + j];
            t[2] = b1[hd * 16 + j];         // k=2: b1 (x K-slot 2 = 1.0)
        }
        a1d = cvt8(t);
        f32x8 s = {0.f,0.f,0.f,0.f,0.f,0.f,0.f,0.f};
        if (h == 0 && row < 16) {           // head 2 in rows 0..15
            s[0] = W1[64 + row];
            s[1] = W1[80 + row];
            s[2] = b1[32 + row];
        }
        a1s = cvt8(s);
    }
    bf16x8 a2[3], a3[3];
    u32x4  b2pk[3];
    #pragma unroll
    for (int e = 0; e < 3; ++e) {
        f32x8 t2v = {0.f,0.f,0.f,0.f,0.f,0.f,0.f,0.f};
        if (row < 16) {
            #pragma unroll
            for (int i = 0; i < 8; ++i) {
                const int k = (i & 3) + 8 * (i >> 2) + 4 * h;   // kperm(h,i)
                t2v[i] = W2[e * 256 + k * 16 + row];
            }
        }
        a2[e] = cvt8(t2v);
        f32x8 t3 = {0.f,0.f,0.f,0.f,0.f,0.f,0.f,0.f};
        if (row == e) {
            #pragma unroll
            for (int i = 0; i < 8; ++i) {
                const int k = (i & 3) + 8 * (i >> 2) + 4 * h;
                t3[i] = W3[e * 16 + k];
            }
        }
        a3[e] = cvt8(t3);
        #pragma unroll
        for (int j = 0; j < 4; ++j) {
            const int k0 = ((2*j) & 3) + 8 * ((2*j) >> 2) + 4 * h;
            const int k1 = ((2*j+1) & 3) + 8 * ((2*j+1) >> 2) + 4 * h;
            b2pk[e][j] = pkcvt((f32x2){ b2[e * 16 + k0], b2[e * 16 + k1] });
        }
    }
    const float b30 = b3[0], b31 = b3[1], b32 = b3[2];
    f32x16 zz;
    #pragma unroll
    for (int r = 0; r < 16; ++r) zz[r] = 0.f;

    const int xoff = (wv * 32 + row) * 8;    // bytes into 1024B x-chunk
    const int ooff = (wv * 32 + row) * 12;   // bytes into 1536B out-chunk (lane<32)

    const int nblk   = n >> 7;               // 128 points per block-iter
    const int stride = (int)gridDim.x;
    const size_t xstep = (size_t)stride * 1024;
    const size_t ostep = (size_t)stride * 1536;

    int cb = (int)blockIdx.x;
    const char* xp = (const char*)x + (size_t)cb * 1024 + xoff;
    char*       op = (char*)out + (size_t)cb * 1536 + ooff;

    float2 xv = *reinterpret_cast<const float2*>(xp);
    float3 pend;
    char*  paddr = nullptr;
    bool   pendv = false;

    while (true) {
        const bool more = (cb + stride) < nblk;
        float2 xn;
        if (more)                             // prefetch next iter's x
            xn = *reinterpret_cast<const float2*>(xp + xstep);

        // previous iteration's store issued here: drain deadline 8 MFMAs away
        if (pendv && lane < 32)
            *reinterpret_cast<float3*>(paddr) = pend;

        // B1 k-slots {x0, x1, 1.0, 0...}
        u32x4 bu = { pkcvt((f32x2){xv.x, xv.y}), 0x3F80u, 0u, 0u };
        const bf16x8 bx = __builtin_bit_cast(bf16x8, bu);

        // ---- Layer 1, serialized through ONE temp t (register diet) ----
        f32x16 t;
        u32x4 w0, w1, w2;
        t = MFMA32(a1d, bx, zz);              // heads 0,1
        #pragma unroll
        for (int j = 0; j < 4; ++j) {
            w0[j] = pkcvt(max2((f32x2){ t[2*j],     t[2*j + 1] }));
            w1[j] = pkcvt(max2((f32x2){ t[8 + 2*j], t[8 + 2*j + 1] }));
        }
        t = MFMA32(a1s, bx, zz);              // head 2 (reuses t's regs)
        #pragma unroll
        for (int j = 0; j < 4; ++j)
            w2[j] = pkcvt(max2((f32x2){ t[2*j], t[2*j + 1] }));
        const bf16x8 bh0 = __builtin_bit_cast(bf16x8, w0);
        const bf16x8 bh1 = __builtin_bit_cast(bf16x8, w1);
        const bf16x8 bh2 = __builtin_bit_cast(bf16x8, w2);

        // ---- Layers 2+3 per head; y chained in place through MFMA3's C ----
        f32x16 y;
        #pragma unroll
        for (int e = 0; e < 3; ++e) {
            const bf16x8 bh = (e == 0) ? bh0 : ((e == 1) ? bh1 : bh2);
            t = MFMA32(a2[e], bh, zz);
            u32x4 bw;
            #pragma unroll
            for (int j = 0; j < 4; ++j) {
                f32x2 q = max2((f32x2){ t[2*j], t[2*j + 1] } + bfexp(b2pk[e][j]));
                bw[j] = pkcvt(q);
            }
            const bf16x8 bt = __builtin_bit_cast(bf16x8, bw);
            y = MFMA32(a3[e], bt, (e == 0) ? zz : y);
        }

        pend  = make_float3(y[0] + b30, y[1] + b31, y[2] + b32);
        paddr = op;
        pendv = true;

        if (!more) break;
        cb += stride;
        xp += xstep;
        op += ostep;
        xv = xn;
    }

    if (pendv && lane < 32)
        *reinterpret_cast<float3*>(paddr) = pend;
}

extern "C" void kernel_launch(void* const* d_in, const int* in_sizes, int n_in,
                              void* d_out, int out_size, void* d_ws, size_t ws_size,
                              hipStream_t stream) {
    const float* x  = (const float*)d_in[0];
    const float* W1 = (const float*)d_in[1];
    const float* b1 = (const float*)d_in[2];
    const float* W2 = (const float*)d_in[3];
    const float* b2 = (const float*)d_in[4];
    const float* W3 = (const float*)d_in[5];
    const float* b3 = (const float*)d_in[6];
    float* out = (float*)d_out;
    (void)d_ws; (void)ws_size; (void)n_in; (void)out_size;

    const int n = in_sizes[0] / 2;   // 4194304 points (32768 * 128)
    const int block = 256;
    const int grid = 2048;           // persistent: 16 chunk-iterations per block

    mlp3_mfma32<<<grid, block, 0, stream>>>(x, W1, b1, W2, b2, W3, b3, out, n);
}